// Round 8
// baseline (178.315 us; speedup 1.0000x reference)
//
#include <hip/hip_runtime.h>
#include <math.h>

#define B 8
#define V 1024
#define E 32
#define H 4
#define HIDN 64
#define CAP 64        // max out-degree capacity; E[deg]=17, P(deg>64) ~ 1e-21
#define MAXNNZ 20480  // nnz ~ 17390 +/- 128; +24 sigma headroom
#define SE (MAXNNZ / V)  // 20 edges per thread in flow kernel
#define ZBLK 128      // zero-role blocks in setup kernel
#define CCBLK 16      // colcount-role blocks in setup kernel

// XCD-aware decode: blockIdx round-robins across 8 XCDs on MI355X, and B==8.
// b = blockIdx & 7 pins each batch to one XCD -> per-XCD working set fits 4MB L2.

__device__ __forceinline__ float wave_sum(float v) {
  for (int o = 32; o > 0; o >>= 1) v += __shfl_xor(v, o);
  return v;
}
__device__ __forceinline__ float wave_max(float v) {
  for (int o = 32; o > 0; o >>= 1) v = fmaxf(v, __shfl_xor(v, o));
  return v;
}

// ---- K1: merged independent setup work (64-thread blocks, role by blockIdx) ----
// roles: [0,V) build_csr; [V,2V) encoder MLP (8 nodes/blk); [2V,3V) transpose
// dec_w2; [3V,3V+ZBLK) zero fwe+meta+slot_cur; [3V+ZBLK,3V+ZBLK+CCBLK) in-degree
// column count (no atomics).
#define ENV 8
__global__ void setup_kernel(const float* __restrict__ adj, const float* __restrict__ demands,
                             const float* __restrict__ emb,
                             const float* __restrict__ ew1, const float* __restrict__ eb1,
                             const float* __restrict__ ew2, const float* __restrict__ eb2,
                             const float* __restrict__ dec_w2,
                             int* __restrict__ nbr, int* __restrict__ deg,
                             int* __restrict__ deg_in, int* __restrict__ slot_cur,
                             float* __restrict__ enc, float* __restrict__ w2t,
                             float* __restrict__ fwe, unsigned int* __restrict__ meta) {
  int blk = blockIdx.x;
  int j = threadIdx.x;  // 64
  if (blk < V) {
    // ---- CSR build (row-coalesced ballot compaction) ----
    int v = blk;
    int base = 0;
    for (int c = 0; c < V; c += 64) {
      float a = adj[v * V + c + j];
      unsigned long long m = __ballot(a > 0.5f);
      int pos = __popcll(m & ((1ull << j) - 1ull));
      if (a > 0.5f && base + pos < CAP) nbr[v * CAP + base + pos] = c + j;
      base += __popcll(m);
    }
    if (j == 0) deg[v] = (base < CAP) ? base : CAP;
  } else if (blk < 2 * V) {
    // ---- encoder MLP for 8 nodes ----
    int eb = blk - V;
    int b = eb & 7;
    int v0 = (eb >> 3) * ENV;
    int bv0 = b * V + v0;
    __shared__ float xs[ENV][E + 1];
    __shared__ float hs[ENV][64];
#pragma unroll
    for (int n = 0; n < ENV; ++n) {
      if (j < E) xs[n][j] = emb[(v0 + n) * E + j];
      else if (j == E) xs[n][E] = demands[b * V + v0 + n];
    }
    __syncthreads();
    float h[ENV];
#pragma unroll
    for (int n = 0; n < ENV; ++n) h[n] = eb1[j];
    for (int i = 0; i < E + 1; ++i) {
      float wv = ew1[i * 64 + j];
#pragma unroll
      for (int n = 0; n < ENV; ++n) h[n] += xs[n][i] * wv;
    }
#pragma unroll
    for (int n = 0; n < ENV; ++n) hs[n][j] = fmaxf(h[n], 0.f);
    __syncthreads();
    float o[ENV];
#pragma unroll
    for (int n = 0; n < ENV; ++n) o[n] = eb2[j];
    for (int i = 0; i < 64; ++i) {
      float wv = ew2[i * 64 + j];
#pragma unroll
      for (int n = 0; n < ENV; ++n) o[n] += hs[n][i] * wv;
    }
#pragma unroll
    for (int n = 0; n < ENV; ++n) enc[(bv0 + n) * 64 + j] = fmaxf(o[n], 0.f);
  } else if (blk < 3 * V) {
    int w = blk - 2 * V;
    w2t[w * 64 + j] = dec_w2[j * V + w];
  } else if (blk < 3 * V + ZBLK) {
    // ---- zero fwe + meta + slot_cur (pad slots must be exactly 0 each launch) ----
    int idx = (blk - 3 * V) * 64 + j;
    for (int i = idx; i < B * MAXNNZ; i += ZBLK * 64) fwe[i] = 0.f;
    for (int i = idx; i < MAXNNZ; i += ZBLK * 64) meta[i] = 0u;
    if (idx < V) slot_cur[idx] = 0;
  } else {
    // ---- in-degree per column, row-coalesced, no atomics ----
    int g = blk - (3 * V + ZBLK);
    int col = g * 64 + j;
    int cnt = 0;
    for (int r = 0; r < V; r += 4) {
      cnt += (adj[(size_t)r * V + col] > 0.5f) ? 1 : 0;
      cnt += (adj[(size_t)(r + 1) * V + col] > 0.5f) ? 1 : 0;
      cnt += (adj[(size_t)(r + 2) * V + col] > 0.5f) ? 1 : 0;
      cnt += (adj[(size_t)(r + 3) * V + col] > 0.5f) ? 1 : 0;
    }
    deg_in[col] = cnt;
  }
}

// ---- K2: per-block redundant scan of deg_in + dest-grouped slot assignment ----
__global__ void csc_fill(const int* __restrict__ deg_in, const int* __restrict__ nbr,
                         const int* __restrict__ deg, int* __restrict__ slot_cur,
                         int* __restrict__ csc_pos) {
  __shared__ int ioff[V];
  int v = blockIdx.x, lane = threadIdx.x;  // 64
  int vals[16];
  int tot = 0;
#pragma unroll
  for (int i = 0; i < 16; ++i) {
    vals[i] = tot;
    tot += deg_in[lane * 16 + i];
  }
  int run = tot;
  for (int o = 1; o < 64; o <<= 1) {
    int u = __shfl_up(run, o);
    if (lane >= o) run += u;
  }
  int excl = run - tot;
#pragma unroll
  for (int i = 0; i < 16; ++i) ioff[lane * 16 + i] = excl + vals[i];
  __syncthreads();
  if (lane < deg[v]) {
    int w = nbr[v * CAP + lane];
    csc_pos[v * CAP + lane] = ioff[w] + atomicAdd(&slot_cur[w], 1);
  }
}

// ---- t = einsum('bvf,hfg->bhvg') + score projections, 8 nodes/block, XCD-pinned ----
#define TNV 8
__global__ void t_kernel(const float* __restrict__ enc, const float* __restrict__ gat_w,
                         const float* __restrict__ a1, const float* __restrict__ a2,
                         float* __restrict__ t, float* __restrict__ s_self,
                         float* __restrict__ s_nbr) {
  int b = blockIdx.x & 7;
  int v0 = (blockIdx.x >> 3) * TNV;
  int bv0 = b * V + v0;
  int tid = threadIdx.x;  // 256
  int h = tid >> 6, g = tid & 63;
  __shared__ float es[TNV][64];
  for (int i = tid; i < TNV * 64; i += 256) es[i >> 6][i & 63] = enc[bv0 * 64 + i];
  __syncthreads();
  float acc[TNV];
#pragma unroll
  for (int n = 0; n < TNV; ++n) acc[n] = 0.f;
  const float* w = gat_w + h * 64 * 64 + g;
  for (int f = 0; f < 64; ++f) {
    float wf = w[f * 64];
#pragma unroll
    for (int n = 0; n < TNV; ++n) acc[n] += es[n][f] * wf;
  }
  float a1v = a1[h * 64 + g], a2v = a2[h * 64 + g];
#pragma unroll
  for (int n = 0; n < TNV; ++n) {
    t[((size_t)(b * H + h) * V + (v0 + n)) * 64 + g] = acc[n];
    float v1 = wave_sum(acc[n] * a1v);
    float v2 = wave_sum(acc[n] * a2v);
    if (g == 0) {
      s_self[(b * H + h) * V + (v0 + n)] = v1;
      s_nbr[(b * H + h) * V + (v0 + n)] = v2;
    }
  }
}

// ---- sparse GAT attention + head-mean + gate, XCD-pinned by batch ----
__global__ void gat_kernel(const float* __restrict__ enc_in, const float* __restrict__ t,
                           const float* __restrict__ s_self, const float* __restrict__ s_nbr,
                           const int* __restrict__ nbr, const int* __restrict__ deg,
                           const float* __restrict__ gate_w, const float* __restrict__ gate_u,
                           const float* __restrict__ gate_b, float* __restrict__ enc_out) {
  int b = blockIdx.x & 7;
  int v = blockIdx.x >> 3;
  int bv = b * V + v;
  int tid = threadIdx.x;
  int h = tid >> 6, lane = tid & 63;
  int dvv = deg[v];
  int wk = (lane < dvv) ? nbr[v * CAP + lane] : 0;
  float logit = -1e30f;
  if (lane < dvv) {
    float x = s_self[(b * H + h) * V + v] + s_nbr[(b * H + h) * V + wk];
    logit = (x > 0.f) ? x : 0.2f * x;  // leaky_relu 0.2
  }
  float m = wave_max(logit);
  float e = (lane < dvv) ? __expf(logit - m) : 0.f;
  float s = wave_sum(e);
  float coef = e / s;
  const float* tb = t + (size_t)(b * H + h) * (V * 64);
  float acc = 0.f;
  for (int k = 0; k < dvv; ++k) {
    float c = __shfl(coef, k);
    int w = __shfl(wk, k);
    acc += c * tb[w * 64 + lane];
  }
  __shared__ float hsum[4][64];
  __shared__ float nxts[64], encs[64];
  hsum[h][lane] = acc;
  __syncthreads();
  if (tid < 64) {
    float s4 = hsum[0][tid] + hsum[1][tid] + hsum[2][tid] + hsum[3][tid];
    nxts[tid] = fmaxf(0.25f * s4, 0.f);
    encs[tid] = enc_in[bv * 64 + tid];
  }
  __syncthreads();
  float part = 0.f;
  for (int f = h * 16; f < h * 16 + 16; ++f)
    part += nxts[f] * gate_w[f * 64 + lane] + encs[f] * gate_u[f * 64 + lane];
  __syncthreads();
  hsum[h][lane] = part;
  __syncthreads();
  if (tid < 64) {
    float zs = hsum[0][tid] + hsum[1][tid] + hsum[2][tid] + hsum[3][tid] + gate_b[tid];
    float z = 1.f / (1.f + __expf(-zs));
    enc_out[bv * 64 + tid] = z * nxts[tid] + (1.f - z) * encs[tid];
  }
}

// ---- K7: fused decoder+dual+flow-weights, 4 nodes/block (1 wave/node in fw),
//      lane-per-edge fw phase (no serial wave reductions); XCD-pinned ----
#define DNV 4
__global__ __launch_bounds__(256) void decfw_kernel(
    const float* __restrict__ enc, const float* __restrict__ dw1,
    const float* __restrict__ db1, const float* __restrict__ uw1,
    const float* __restrict__ ub1, const float* __restrict__ uw2,
    const float* __restrict__ ub2, const float* __restrict__ w2t,
    const float* __restrict__ dec_b2, const int* __restrict__ nbr,
    const int* __restrict__ deg, const int* __restrict__ csc_pos,
    float* __restrict__ fwe, unsigned int* __restrict__ meta,
    float* __restrict__ rssq, float* __restrict__ dvout) {
  int b = blockIdx.x & 7;
  int v0 = (blockIdx.x >> 3) * DNV;
  int bv0 = b * V + v0;
  int tid = threadIdx.x;  // 256
  int wv = tid >> 6, j = tid & 63;
  __shared__ float es[DNV][64];
  __shared__ float hs[DNV][64];
  es[wv][j] = enc[(bv0 + wv) * 64 + j];
  __syncthreads();
  // dec phase: wave wv computes node v0+wv's hid (linear) and dual scalar
  float hj = db1[j], uj = ub1[j];
  for (int f = 0; f < 64; ++f) {
    hj += es[wv][f] * dw1[f * 64 + j];
    uj += es[wv][f] * uw1[f * 64 + j];
  }
  hs[wv][j] = hj;
  float sdv = wave_sum(uj * uw2[j]);
  if (j == 0) dvout[bv0 + wv] = sdv + ub2[0];
  __syncthreads();
  // fw phase: wave wv, node v0+wv; lane j owns edge j
  int v = v0 + wv;
  int dvv = deg[v];
  int w = (j < dvv) ? nbr[v * CAP + j] : 0;
  const float4* wrow = (const float4*)(w2t + w * 64);
  const float4* hv4 = (const float4*)hs[wv];
  float d = 0.f;
#pragma unroll
  for (int f = 0; f < 16; ++f) {
    float4 wvv = wrow[f];
    float4 hv = hv4[f];  // LDS broadcast (all lanes same address)
    d += hv.x * wvv.x + hv.y * wvv.y + hv.z * wvv.z + hv.w * wvv.w;
  }
  d += dec_b2[w];
  float pp = d * d;
  float myp = (j < dvv) ? pp : -1e30f;
  float m = wave_max(myp);
  float e = (j < dvv) ? __expf(myp - m) : 0.f;
  float s = wave_sum(e);
  float coef = e / s;
  if (j < dvv) {
    int idx = csc_pos[v * CAP + j];
    fwe[(size_t)b * MAXNNZ + idx] = coef;
    meta[idx] = (unsigned)v | ((unsigned)w << 16);
  }
  float r = wave_sum(coef * coef);
  if (j == 0) rssq[bv0 + wv] = r;
}

// ---- K8: flow iterations with register-cached edges + LDS scatter ----
__global__ __launch_bounds__(1024) void flow_dual_kernel(
    const float* __restrict__ fwe, const unsigned int* __restrict__ meta,
    const float* __restrict__ rssq, const float* __restrict__ dv,
    const float* __restrict__ demands, const int* __restrict__ nbr_out,
    const int* __restrict__ deg_out, float* __restrict__ partial) {
  int b = blockIdx.x;
  int v = threadIdx.x;  // 1024
  __shared__ float o[V], infl[V], dvs[V];
  __shared__ float red[16];
  float dem = demands[b * V + v];
  dvs[v] = dv[b * V + v];
  o[v] = fmaxf(-dem, 0.f);  // o_1 = relu(-demand)
  infl[v] = 0.f;
  // stage this thread's 20 edges into registers (pads are exact zeros)
  const float4* fp = (const float4*)(fwe + (size_t)b * MAXNNZ + v * SE);
  const uint4* mp = (const uint4*)(meta + v * SE);
  float fr[SE];
  unsigned mr[SE];
#pragma unroll
  for (int i = 0; i < SE / 4; ++i) {
    float4 f4 = fp[i];
    uint4 m4 = mp[i];
    fr[4 * i + 0] = f4.x; fr[4 * i + 1] = f4.y; fr[4 * i + 2] = f4.z; fr[4 * i + 3] = f4.w;
    mr[4 * i + 0] = m4.x; mr[4 * i + 1] = m4.y; mr[4 * i + 2] = m4.z; mr[4 * i + 3] = m4.w;
  }
  __syncthreads();
  for (int it = 0; it < 9; ++it) {
    float acc = 0.f;
    int pdst = -1;
#pragma unroll
    for (int i = 0; i < SE; ++i) {
      int src = mr[i] & 0xFFFF;
      int dst = mr[i] >> 16;
      if (dst != pdst) {
        if (acc != 0.f) atomicAdd(&infl[pdst], acc);
        acc = 0.f;
        pdst = dst;
      }
      acc += fr[i] * o[src];
    }
    if (acc != 0.f) atomicAdd(&infl[pdst], acc);
    __syncthreads();  // scatter complete (implies all reads of o done)
    float nv = fmaxf(infl[v] - dem, 0.f);
    o[v] = nv;
    infl[v] = 0.f;
    __syncthreads();  // update visible before next scatter
  }
  float o10 = o[v];
  float local = o10 * o10 * rssq[b * V + v];  // flow_cost contribution
  // dual: 0.25*sum_edges relu(dv_v - dv_w)^2 + sum_v dv_v*dem_v
  float dvv = dvs[v];
  int dout = deg_out[v];
  float acc = 0.f;
  for (int k = 0; k < dout; ++k) {
    float diff = dvv - dvs[nbr_out[v * CAP + k]];
    if (diff > 0.f) acc += diff * diff;
  }
  local += 0.25f * acc + dvv * dem;
  local = wave_sum(local);
  if ((v & 63) == 0) red[v >> 6] = local;
  __syncthreads();
  if (v < 16) {
    float r = red[v];
    for (int o2 = 8; o2 > 0; o2 >>= 1) r += __shfl_xor(r, o2, 16);
    if (v == 0) partial[b] = r;
  }
}

__global__ void final_kernel(const float* __restrict__ partial, float* __restrict__ out) {
  if (threadIdx.x == 0) {
    float s = 0.f;
    for (int b = 0; b < B; ++b) s += partial[b];
    out[0] = s * (1.0f / B);
  }
}

extern "C" void kernel_launch(void* const* d_in, const int* in_sizes, int n_in,
                              void* d_out, int out_size, void* d_ws, size_t ws_size,
                              hipStream_t stream) {
  const float* demands = (const float*)d_in[0];
  const float* emb     = (const float*)d_in[1];
  const float* adj     = (const float*)d_in[2];
  const float* enc_w1  = (const float*)d_in[3];
  const float* enc_b1  = (const float*)d_in[4];
  const float* enc_w2  = (const float*)d_in[5];
  const float* enc_b2  = (const float*)d_in[6];
  const float* gat_w   = (const float*)d_in[7];
  const float* gat_a1  = (const float*)d_in[8];
  const float* gat_a2  = (const float*)d_in[9];
  const float* gate_w  = (const float*)d_in[10];
  const float* gate_u  = (const float*)d_in[11];
  const float* gate_b  = (const float*)d_in[12];
  const float* dec_w1  = (const float*)d_in[13];
  const float* dec_b1  = (const float*)d_in[14];
  const float* dec_w2  = (const float*)d_in[15];
  const float* dec_b2  = (const float*)d_in[16];
  const float* dual_w1 = (const float*)d_in[17];
  const float* dual_b1 = (const float*)d_in[18];
  const float* dual_w2 = (const float*)d_in[19];
  const float* dual_b2 = (const float*)d_in[20];

  char* p = (char*)d_ws;
  auto alloc = [&](size_t n) { void* r = (void*)p; p += (n + 255) & ~(size_t)255; return r; };
  int* nbr_out   = (int*)alloc((size_t)V * CAP * 4);
  int* deg_out   = (int*)alloc((size_t)V * 4);
  int* deg_in    = (int*)alloc((size_t)V * 4);
  int* slot_cur  = (int*)alloc((size_t)V * 4);
  int* csc_pos   = (int*)alloc((size_t)V * CAP * 4);
  float* fwe     = (float*)alloc((size_t)B * MAXNNZ * 4);
  unsigned int* meta = (unsigned int*)alloc((size_t)MAXNNZ * 4);
  float* w2t     = (float*)alloc((size_t)HIDN * V * 4);
  float* encA    = (float*)alloc((size_t)B * V * 64 * 4);
  float* encB    = (float*)alloc((size_t)B * V * 64 * 4);
  float* t       = (float*)alloc((size_t)B * H * V * 64 * 4);
  float* s_self  = (float*)alloc((size_t)B * H * V * 4);
  float* s_nbr   = (float*)alloc((size_t)B * H * V * 4);
  float* dv      = (float*)alloc((size_t)B * V * 4);
  float* rssq    = (float*)alloc((size_t)B * V * 4);
  float* partial = (float*)alloc((size_t)B * 4);

  setup_kernel<<<3 * V + ZBLK + CCBLK, 64, 0, stream>>>(
      adj, demands, emb, enc_w1, enc_b1, enc_w2, enc_b2, dec_w2,
      nbr_out, deg_out, deg_in, slot_cur, encA, w2t, fwe, meta);
  csc_fill<<<V, 64, 0, stream>>>(deg_in, nbr_out, deg_out, slot_cur, csc_pos);
  float* cur = encA;
  float* nxt = encB;
  for (int l = 0; l < 2; ++l) {
    t_kernel<<<B * V / TNV, 256, 0, stream>>>(cur, gat_w, gat_a1, gat_a2, t, s_self, s_nbr);
    gat_kernel<<<B * V, 256, 0, stream>>>(cur, t, s_self, s_nbr, nbr_out, deg_out,
                                          gate_w, gate_u, gate_b, nxt);
    float* tmp = cur; cur = nxt; nxt = tmp;
  }
  decfw_kernel<<<B * V / DNV, 256, 0, stream>>>(cur, dec_w1, dec_b1, dual_w1, dual_b1,
                                                dual_w2, dual_b2, w2t, dec_b2, nbr_out,
                                                deg_out, csc_pos, fwe, meta, rssq, dv);
  flow_dual_kernel<<<B, 1024, 0, stream>>>(fwe, meta, rssq, dv, demands, nbr_out, deg_out,
                                           partial);
  final_kernel<<<1, 64, 0, stream>>>(partial, (float*)d_out);
}

// Round 9
// 150.922 us; speedup vs baseline: 1.1815x; 1.1815x over previous
//
#include <hip/hip_runtime.h>
#include <math.h>

#define B 8
#define V 1024
#define E 32
#define H 4
#define HIDN 64
#define CAP 64        // max out-degree capacity; E[deg]=17, P(deg>64) ~ 1e-21
#define MAXNNZ 20480  // nnz ~ 17390 +/- 128; +24 sigma headroom
#define SE (MAXNNZ / V)  // 20 edges per thread in flow kernel
#define ZBLK 128      // zero-role blocks in setup kernel

// XCD-aware decode: blockIdx round-robins across 8 XCDs on MI355X, and B==8.
// b = blockIdx & 7 pins each batch to one XCD -> per-XCD working set fits 4MB L2.

__device__ __forceinline__ float wave_sum(float v) {
  for (int o = 32; o > 0; o >>= 1) v += __shfl_xor(v, o);
  return v;
}
__device__ __forceinline__ float wave_max(float v) {
  for (int o = 32; o > 0; o >>= 1) v = fmaxf(v, __shfl_xor(v, o));
  return v;
}

// ---- K0: zero in-degree counters + precompute wa1/wa2 = gat_w @ a1/a2 ----
__global__ void zero_wa_kernel(int* __restrict__ deg_in, const float* __restrict__ gat_w,
                               const float* __restrict__ a1, const float* __restrict__ a2,
                               float* __restrict__ wa1, float* __restrict__ wa2) {
  if (blockIdx.x < 4) {
    deg_in[blockIdx.x * 256 + threadIdx.x] = 0;
  } else {
    int h = threadIdx.x >> 6, f = threadIdx.x & 63;
    float s1 = 0.f, s2 = 0.f;
    const float* W = gat_w + h * 4096 + f * 64;
    for (int g = 0; g < 64; ++g) {
      float w = W[g];
      s1 += w * a1[h * 64 + g];
      s2 += w * a2[h * 64 + g];
    }
    wa1[h * 64 + f] = s1;
    wa2[h * 64 + f] = s2;
  }
}

// ---- K1: merged setup (64-thread blocks, role by blockIdx) ----
// roles: [0,V) build_csr + atomic in-degree; [V,2V) encoder MLP + layer-1 scores;
//        [2V,3V) transpose dec_w2; [3V,3V+ZBLK) zero fwe+meta.
#define ENV 8
__global__ void setup_kernel(const float* __restrict__ adj, const float* __restrict__ demands,
                             const float* __restrict__ emb,
                             const float* __restrict__ ew1, const float* __restrict__ eb1,
                             const float* __restrict__ ew2, const float* __restrict__ eb2,
                             const float* __restrict__ dec_w2,
                             const float* __restrict__ wa1, const float* __restrict__ wa2,
                             int* __restrict__ nbr, int* __restrict__ deg,
                             int* __restrict__ deg_in, float* __restrict__ enc,
                             float* __restrict__ ss, float* __restrict__ sn,
                             float* __restrict__ w2t, float* __restrict__ fwe,
                             unsigned int* __restrict__ meta) {
  int blk = blockIdx.x;
  int j = threadIdx.x;  // 64
  if (blk < V) {
    // ---- CSR build (row-coalesced ballot compaction) + kept-edge in-degree ----
    int v = blk;
    int base = 0;
    for (int c = 0; c < V; c += 64) {
      float a = adj[v * V + c + j];
      unsigned long long m = __ballot(a > 0.5f);
      int pos = __popcll(m & ((1ull << j) - 1ull));
      if (a > 0.5f && base + pos < CAP) {
        nbr[v * CAP + base + pos] = c + j;
        atomicAdd(&deg_in[c + j], 1);
      }
      base += __popcll(m);
    }
    if (j == 0) deg[v] = (base < CAP) ? base : CAP;
  } else if (blk < 2 * V) {
    // ---- encoder MLP for 8 nodes + layer-1 attention scores ----
    int eb = blk - V;
    int b = eb & 7;
    int v0 = (eb >> 3) * ENV;
    int bv0 = b * V + v0;
    __shared__ float xs[ENV][E + 1];
    __shared__ float hs[ENV][64];
#pragma unroll
    for (int n = 0; n < ENV; ++n) {
      if (j < E) xs[n][j] = emb[(v0 + n) * E + j];
      else if (j == E) xs[n][E] = demands[b * V + v0 + n];
    }
    __syncthreads();
    float h[ENV];
#pragma unroll
    for (int n = 0; n < ENV; ++n) h[n] = eb1[j];
    for (int i = 0; i < E + 1; ++i) {
      float wv = ew1[i * 64 + j];
#pragma unroll
      for (int n = 0; n < ENV; ++n) h[n] += xs[n][i] * wv;
    }
#pragma unroll
    for (int n = 0; n < ENV; ++n) hs[n][j] = fmaxf(h[n], 0.f);
    __syncthreads();
    float o[ENV];
#pragma unroll
    for (int n = 0; n < ENV; ++n) o[n] = eb2[j];
    for (int i = 0; i < 64; ++i) {
      float wv = ew2[i * 64 + j];
#pragma unroll
      for (int n = 0; n < ENV; ++n) o[n] += hs[n][i] * wv;
    }
#pragma unroll
    for (int n = 0; n < ENV; ++n) {
      o[n] = fmaxf(o[n], 0.f);
      enc[(bv0 + n) * 64 + j] = o[n];
    }
    // layer-1 scores: s_self/s_nbr[h][v] = enc_v . wa{1,2}[h]
#pragma unroll
    for (int n = 0; n < ENV; ++n) {
#pragma unroll
      for (int hh = 0; hh < H; ++hh) {
        float v1 = wave_sum(o[n] * wa1[hh * 64 + j]);
        float v2 = wave_sum(o[n] * wa2[hh * 64 + j]);
        if (j == 0) {
          ss[(b * H + hh) * V + v0 + n] = v1;
          sn[(b * H + hh) * V + v0 + n] = v2;
        }
      }
    }
  } else if (blk < 3 * V) {
    int w = blk - 2 * V;
    w2t[w * 64 + j] = dec_w2[j * V + w];
  } else {
    // ---- zero fwe + meta so pad slots are exactly 0 each launch ----
    int idx = (blk - 3 * V) * 64 + j;
    for (int i = idx; i < B * MAXNNZ; i += ZBLK * 64) fwe[i] = 0.f;
    for (int i = idx; i < MAXNNZ; i += ZBLK * 64) meta[i] = 0u;
  }
}

// ---- K2: exclusive scan of deg_in -> in_off[V+1], single wave ----
__global__ void scan_kernel(const int* __restrict__ deg_in, int* __restrict__ in_off) {
  int lane = threadIdx.x;  // 64
  int vals[16];
  int tot = 0;
#pragma unroll
  for (int i = 0; i < 16; ++i) {
    vals[i] = tot;
    tot += deg_in[lane * 16 + i];
  }
  int run = tot;
  for (int o = 1; o < 64; o <<= 1) {
    int u = __shfl_up(run, o);
    if (lane >= o) run += u;
  }
  int excl = run - tot;
#pragma unroll
  for (int i = 0; i < 16; ++i) in_off[lane * 16 + i] = excl + vals[i];
  if (lane == 63) in_off[V] = excl + tot;
}

// ---- K3: assign each CSR edge a dest-grouped slot via atomic countdown ----
__global__ void csc_fill(const int* __restrict__ nbr, const int* __restrict__ deg,
                         int* __restrict__ deg_in, const int* __restrict__ in_off,
                         int* __restrict__ csc_pos) {
  int v = blockIdx.x, k = threadIdx.x;
  if (k < deg[v]) {
    int w = nbr[v * CAP + k];
    int old = atomicSub(&deg_in[w], 1);
    csc_pos[v * CAP + k] = in_off[w] + old - 1;
  }
}

// ---- K4/K5: GAT layer without materializing t: aggregate-then-project.
// 8 nodes/block (amortizes gat_w + gate weights 8x); XCD-pinned by batch. ----
#define GNV 8
__global__ __launch_bounds__(256) void gat2_kernel(
    const float* __restrict__ enc_in, const float* __restrict__ ss_in,
    const float* __restrict__ sn_in, const int* __restrict__ nbr,
    const int* __restrict__ deg, const float* __restrict__ gat_w,
    const float* __restrict__ gate_w, const float* __restrict__ gate_u,
    const float* __restrict__ gate_b, const float* __restrict__ wa1,
    const float* __restrict__ wa2, float* __restrict__ enc_out,
    float* __restrict__ ss_out, float* __restrict__ sn_out, int write_s) {
  int b = blockIdx.x & 7;
  int v0 = (blockIdx.x >> 3) * GNV;
  int tid = threadIdx.x;  // 256
  int wid = tid >> 6, lane = tid & 63;
  __shared__ float agg[GNV][H][64];   // 8 KB
  __shared__ float gpart[GNV][4][64]; // 8 KB (heads, then gate partials)
  __shared__ float nxts[GNV][64];     // 2 KB
  __shared__ float encs[GNV][64];     // 2 KB
  const float* eb = enc_in + (size_t)b * V * 64;
  for (int i = tid; i < GNV * 64; i += 256) encs[i >> 6][i & 63] = eb[v0 * 64 + i];
  // P1: attention softmax + enc aggregation; wave wid handles nodes wid, wid+4
  for (int n = wid; n < GNV; n += 4) {
    int v = v0 + n;
    int dvv = deg[v];
    int wk = (lane < dvv) ? nbr[v * CAP + lane] : 0;
    float c[H];
#pragma unroll
    for (int h = 0; h < H; ++h) {
      float x = ss_in[(b * H + h) * V + v] + sn_in[(b * H + h) * V + wk];
      x = (x > 0.f) ? x : 0.2f * x;  // leaky_relu 0.2
      if (lane >= dvv) x = -1e30f;
      float m = wave_max(x);
      float e = (lane < dvv) ? __expf(x - m) : 0.f;
      float s = wave_sum(e);
      c[h] = e / s;
    }
    float a0 = 0.f, a1v = 0.f, a2v = 0.f, a3v = 0.f;
    for (int k = 0; k < dvv; ++k) {
      int w = __shfl(wk, k);
      float ev = eb[w * 64 + lane];  // one 256B gather serves all 4 heads
      a0 += __shfl(c[0], k) * ev;
      a1v += __shfl(c[1], k) * ev;
      a2v += __shfl(c[2], k) * ev;
      a3v += __shfl(c[3], k) * ev;
    }
    agg[n][0][lane] = a0;
    agg[n][1][lane] = a1v;
    agg[n][2][lane] = a2v;
    agg[n][3][lane] = a3v;
  }
  __syncthreads();
  // P2: heads[n][wid][g] = agg[n][wid] @ W_wid; W rows read once per 8 nodes
  {
    const float* W = gat_w + wid * 4096;
    float hv[GNV];
#pragma unroll
    for (int n = 0; n < GNV; ++n) hv[n] = 0.f;
    for (int f = 0; f < 64; ++f) {
      float wf = W[f * 64 + lane];
#pragma unroll
      for (int n = 0; n < GNV; ++n) hv[n] += agg[n][wid][f] * wf;
    }
#pragma unroll
    for (int n = 0; n < GNV; ++n) gpart[n][wid][lane] = hv[n];
  }
  __syncthreads();
  for (int i = tid; i < GNV * 64; i += 256) {
    int n = i >> 6, g = i & 63;
    float s4 = gpart[n][0][g] + gpart[n][1][g] + gpart[n][2][g] + gpart[n][3][g];
    nxts[n][g] = fmaxf(0.25f * s4, 0.f);
  }
  __syncthreads();
  // P3: gate z = sigmoid(nxt@gate_w + enc@gate_u + b); wave wid covers 16 f-rows
  {
    float part[GNV];
#pragma unroll
    for (int n = 0; n < GNV; ++n) part[n] = 0.f;
    for (int f = wid * 16; f < wid * 16 + 16; ++f) {
      float gw = gate_w[f * 64 + lane], gu = gate_u[f * 64 + lane];
#pragma unroll
      for (int n = 0; n < GNV; ++n) part[n] += nxts[n][f] * gw + encs[n][f] * gu;
    }
    __syncthreads();  // gpart heads no longer needed
#pragma unroll
    for (int n = 0; n < GNV; ++n) gpart[n][wid][lane] = part[n];
  }
  __syncthreads();
  for (int i = tid; i < GNV * 64; i += 256) {
    int n = i >> 6, g = i & 63;
    float zs = gpart[n][0][g] + gpart[n][1][g] + gpart[n][2][g] + gpart[n][3][g] + gate_b[g];
    float z = 1.f / (1.f + __expf(-zs));
    float out = z * nxts[n][g] + (1.f - z) * encs[n][g];
    encs[n][g] = out;  // reuse as output buffer
    enc_out[((size_t)b * V + v0 + n) * 64 + g] = out;
  }
  if (write_s) {
    __syncthreads();
    float w1v = wa1[wid * 64 + lane], w2v = wa2[wid * 64 + lane];
#pragma unroll
    for (int n = 0; n < GNV; ++n) {
      float e = encs[n][lane];
      float ssv = wave_sum(e * w1v);
      float snv = wave_sum(e * w2v);
      if (lane == 0) {
        ss_out[(b * H + wid) * V + v0 + n] = ssv;
        sn_out[(b * H + wid) * V + v0 + n] = snv;
      }
    }
  }
}

// ---- K6: decoder hidden (linear) + dual variable dv, 8 nodes/block, XCD-pinned ----
#define DNV 8
__global__ void dec_dual_kernel(const float* __restrict__ enc, const float* __restrict__ dw1,
                                const float* __restrict__ db1, const float* __restrict__ uw1,
                                const float* __restrict__ ub1, const float* __restrict__ uw2,
                                const float* __restrict__ ub2, float* __restrict__ hid,
                                float* __restrict__ dv) {
  int b = blockIdx.x & 7;
  int v0 = (blockIdx.x >> 3) * DNV;
  int bv0 = b * V + v0;
  int j = threadIdx.x;  // 64
  __shared__ float es[DNV][64];
#pragma unroll
  for (int n = 0; n < DNV; ++n) es[n][j] = enc[(bv0 + n) * 64 + j];
  __syncthreads();
  float hj[DNV], uj[DNV];
#pragma unroll
  for (int n = 0; n < DNV; ++n) { hj[n] = db1[j]; uj[n] = ub1[j]; }
  for (int f = 0; f < 64; ++f) {
    float a = dw1[f * 64 + j], c = uw1[f * 64 + j];
#pragma unroll
    for (int n = 0; n < DNV; ++n) {
      hj[n] += es[n][f] * a;
      uj[n] += es[n][f] * c;
    }
  }
  float w2v = uw2[j];
#pragma unroll
  for (int n = 0; n < DNV; ++n) {
    hid[(bv0 + n) * 64 + j] = hj[n];  // NO relu: decoder is linear
    float s = wave_sum(uj[n] * w2v);
    if (j == 0) dv[bv0 + n] = s + ub2[0];
  }
}

// ---- K7: flow weights: lane-per-edge dot products, softmax over out-edges of
//      pred^2, scatter to CSC slots; XCD-pinned ----
__global__ void fw_kernel(const float* __restrict__ hid, const float* __restrict__ w2t,
                          const float* __restrict__ b2, const int* __restrict__ nbr,
                          const int* __restrict__ deg, const int* __restrict__ csc_pos,
                          float* __restrict__ fwe, unsigned int* __restrict__ meta,
                          float* __restrict__ rssq) {
  int b = blockIdx.x & 7;
  int v = blockIdx.x >> 3;
  int bv = b * V + v;
  int k = threadIdx.x;  // 64; lane k owns edge k
  __shared__ float hs[64];
  hs[k] = hid[bv * 64 + k];
  __syncthreads();
  int dvv = deg[v];
  int w = (k < dvv) ? nbr[v * CAP + k] : 0;
  const float4* wrow = (const float4*)(w2t + w * 64);
  const float4* hv4 = (const float4*)hs;
  float d = 0.f;
#pragma unroll
  for (int f = 0; f < 16; ++f) {
    float4 wv = wrow[f];
    float4 hv = hv4[f];  // LDS broadcast
    d += hv.x * wv.x + hv.y * wv.y + hv.z * wv.z + hv.w * wv.w;
  }
  d += b2[w];
  float pp = d * d;
  float myp = (k < dvv) ? pp : -1e30f;
  float m = wave_max(myp);
  float e = (k < dvv) ? __expf(myp - m) : 0.f;
  float s = wave_sum(e);
  float coef = e / s;
  if (k < dvv) {
    int idx = csc_pos[v * CAP + k];
    fwe[(size_t)b * MAXNNZ + idx] = coef;
    meta[idx] = (unsigned)v | ((unsigned)w << 16);
  }
  float r = wave_sum(coef * coef);
  if (k == 0) rssq[bv] = r;
}

// ---- K8: flow iterations with register-cached edges + LDS scatter ----
__global__ __launch_bounds__(1024) void flow_dual_kernel(
    const float* __restrict__ fwe, const unsigned int* __restrict__ meta,
    const float* __restrict__ rssq, const float* __restrict__ dv,
    const float* __restrict__ demands, const int* __restrict__ nbr_out,
    const int* __restrict__ deg_out, float* __restrict__ partial) {
  int b = blockIdx.x;
  int v = threadIdx.x;  // 1024
  __shared__ float o[V], infl[V], dvs[V];
  __shared__ float red[16];
  float dem = demands[b * V + v];
  dvs[v] = dv[b * V + v];
  o[v] = fmaxf(-dem, 0.f);  // o_1 = relu(-demand)
  infl[v] = 0.f;
  const float4* fp = (const float4*)(fwe + (size_t)b * MAXNNZ + v * SE);
  const uint4* mp = (const uint4*)(meta + v * SE);
  float fr[SE];
  unsigned mr[SE];
#pragma unroll
  for (int i = 0; i < SE / 4; ++i) {
    float4 f4 = fp[i];
    uint4 m4 = mp[i];
    fr[4 * i + 0] = f4.x; fr[4 * i + 1] = f4.y; fr[4 * i + 2] = f4.z; fr[4 * i + 3] = f4.w;
    mr[4 * i + 0] = m4.x; mr[4 * i + 1] = m4.y; mr[4 * i + 2] = m4.z; mr[4 * i + 3] = m4.w;
  }
  __syncthreads();
  for (int it = 0; it < 9; ++it) {
    float acc = 0.f;
    int pdst = -1;
#pragma unroll
    for (int i = 0; i < SE; ++i) {
      int src = mr[i] & 0xFFFF;
      int dst = mr[i] >> 16;
      if (dst != pdst) {
        if (acc != 0.f) atomicAdd(&infl[pdst], acc);
        acc = 0.f;
        pdst = dst;
      }
      acc += fr[i] * o[src];
    }
    if (acc != 0.f) atomicAdd(&infl[pdst], acc);
    __syncthreads();
    float nv = fmaxf(infl[v] - dem, 0.f);
    o[v] = nv;
    infl[v] = 0.f;
    __syncthreads();
  }
  float o10 = o[v];
  float local = o10 * o10 * rssq[b * V + v];
  float dvv = dvs[v];
  int dout = deg_out[v];
  float acc = 0.f;
  for (int k = 0; k < dout; ++k) {
    float diff = dvv - dvs[nbr_out[v * CAP + k]];
    if (diff > 0.f) acc += diff * diff;
  }
  local += 0.25f * acc + dvv * dem;
  local = wave_sum(local);
  if ((v & 63) == 0) red[v >> 6] = local;
  __syncthreads();
  if (v < 16) {
    float r = red[v];
    for (int o2 = 8; o2 > 0; o2 >>= 1) r += __shfl_xor(r, o2, 16);
    if (v == 0) partial[b] = r;
  }
}

__global__ void final_kernel(const float* __restrict__ partial, float* __restrict__ out) {
  if (threadIdx.x == 0) {
    float s = 0.f;
    for (int b = 0; b < B; ++b) s += partial[b];
    out[0] = s * (1.0f / B);
  }
}

extern "C" void kernel_launch(void* const* d_in, const int* in_sizes, int n_in,
                              void* d_out, int out_size, void* d_ws, size_t ws_size,
                              hipStream_t stream) {
  const float* demands = (const float*)d_in[0];
  const float* emb     = (const float*)d_in[1];
  const float* adj     = (const float*)d_in[2];
  const float* enc_w1  = (const float*)d_in[3];
  const float* enc_b1  = (const float*)d_in[4];
  const float* enc_w2  = (const float*)d_in[5];
  const float* enc_b2  = (const float*)d_in[6];
  const float* gat_w   = (const float*)d_in[7];
  const float* gat_a1  = (const float*)d_in[8];
  const float* gat_a2  = (const float*)d_in[9];
  const float* gate_w  = (const float*)d_in[10];
  const float* gate_u  = (const float*)d_in[11];
  const float* gate_b  = (const float*)d_in[12];
  const float* dec_w1  = (const float*)d_in[13];
  const float* dec_b1  = (const float*)d_in[14];
  const float* dec_w2  = (const float*)d_in[15];
  const float* dec_b2  = (const float*)d_in[16];
  const float* dual_w1 = (const float*)d_in[17];
  const float* dual_b1 = (const float*)d_in[18];
  const float* dual_w2 = (const float*)d_in[19];
  const float* dual_b2 = (const float*)d_in[20];

  char* p = (char*)d_ws;
  auto alloc = [&](size_t n) { void* r = (void*)p; p += (n + 255) & ~(size_t)255; return r; };
  int* nbr_out   = (int*)alloc((size_t)V * CAP * 4);
  int* deg_out   = (int*)alloc((size_t)V * 4);
  int* deg_in    = (int*)alloc((size_t)V * 4);
  int* in_off    = (int*)alloc((size_t)(V + 1) * 4);
  int* csc_pos   = (int*)alloc((size_t)V * CAP * 4);
  float* fwe     = (float*)alloc((size_t)B * MAXNNZ * 4);
  unsigned int* meta = (unsigned int*)alloc((size_t)MAXNNZ * 4);
  float* w2t     = (float*)alloc((size_t)HIDN * V * 4);
  float* wa1     = (float*)alloc((size_t)H * 64 * 4);
  float* wa2     = (float*)alloc((size_t)H * 64 * 4);
  float* encA    = (float*)alloc((size_t)B * V * 64 * 4);
  float* encB    = (float*)alloc((size_t)B * V * 64 * 4);
  float* ssA     = (float*)alloc((size_t)B * H * V * 4);
  float* snA     = (float*)alloc((size_t)B * H * V * 4);
  float* ssB     = (float*)alloc((size_t)B * H * V * 4);
  float* snB     = (float*)alloc((size_t)B * H * V * 4);
  float* hid     = (float*)alloc((size_t)B * V * 64 * 4);
  float* dv      = (float*)alloc((size_t)B * V * 4);
  float* rssq    = (float*)alloc((size_t)B * V * 4);
  float* partial = (float*)alloc((size_t)B * 4);

  zero_wa_kernel<<<5, 256, 0, stream>>>(deg_in, gat_w, gat_a1, gat_a2, wa1, wa2);
  setup_kernel<<<3 * V + ZBLK, 64, 0, stream>>>(
      adj, demands, emb, enc_w1, enc_b1, enc_w2, enc_b2, dec_w2, wa1, wa2,
      nbr_out, deg_out, deg_in, encA, ssA, snA, w2t, fwe, meta);
  scan_kernel<<<1, 64, 0, stream>>>(deg_in, in_off);
  csc_fill<<<V, 64, 0, stream>>>(nbr_out, deg_out, deg_in, in_off, csc_pos);
  gat2_kernel<<<B * V / GNV, 256, 0, stream>>>(encA, ssA, snA, nbr_out, deg_out, gat_w,
                                               gate_w, gate_u, gate_b, wa1, wa2,
                                               encB, ssB, snB, 1);
  gat2_kernel<<<B * V / GNV, 256, 0, stream>>>(encB, ssB, snB, nbr_out, deg_out, gat_w,
                                               gate_w, gate_u, gate_b, wa1, wa2,
                                               encA, ssA, snA, 0);
  dec_dual_kernel<<<B * V / DNV, 64, 0, stream>>>(encA, dec_w1, dec_b1, dual_w1, dual_b1,
                                                  dual_w2, dual_b2, hid, dv);
  fw_kernel<<<B * V, 64, 0, stream>>>(hid, w2t, dec_b2, nbr_out, deg_out, csc_pos,
                                      fwe, meta, rssq);
  flow_dual_kernel<<<B, 1024, 0, stream>>>(fwe, meta, rssq, dv, demands, nbr_out, deg_out,
                                           partial);
  final_kernel<<<1, 64, 0, stream>>>(partial, (float*)d_out);
}